// Round 5
// baseline (40.863 us; speedup 1.0000x reference)
//
#include <hip/hip_runtime.h>
#include <hip/hip_bf16.h>
#include <cstdint>

// Problem constants: B=16, T=1024, D=256, K=1024
#define M_ROWS 16384   // B*T
#define D_DIM  256
#define K_ROWS 1024

typedef __bf16 bf16x8 __attribute__((ext_vector_type(8)));
typedef float  f32x4  __attribute__((ext_vector_type(4)));

// ---------------------------------------------------------------------------
// Fully fused: out[m,k] = -p * (||x_m||^2 - 2*dot(x_m,c_k) + ||c_k||^2)
//
// One dispatch. 128x128 output tile per block, BK=64, 4 waves (2x2),
// mfma_f32_16x16x32_bf16, operands swapped so the D reg axis is the output
// COLUMN (f32x4 stores). Staging reads f32 inputs directly, converts to bf16
// in registers, ds_write_b128 at XOR-swizzled addresses, and accumulates the
// exact-f32 row squared-norms on the fly.
//
// Staging thread-map and all LDS addressing are byte-identical to the
// round-3 PASSING kernel (srow=tid>>3, sg=tid&7, 4 passes at +n*4096,
// swizzle LDS[row][g] = G[row][g ^ (row&7)], g = 16B granule). The only
// change vs round 3's gemm: source is f32 (two f32x4 per granule) with
// in-register cvt + norm accumulation, and norms come from LDS in the
// epilogue. No lambdas; plain unrolled macro.
// ---------------------------------------------------------------------------

#define LOADCVT(k0)                                                            \
  do {                                                                         \
    _Pragma("unroll")                                                          \
    for (int n = 0; n < 4; ++n) {                                              \
      const f32x4 a0 = *reinterpret_cast<const f32x4*>(gA + (size_t)(n * 32) * D_DIM + (k0));     \
      const f32x4 a1 = *reinterpret_cast<const f32x4*>(gA + (size_t)(n * 32) * D_DIM + (k0) + 4); \
      const f32x4 b0 = *reinterpret_cast<const f32x4*>(gB + (size_t)(n * 32) * D_DIM + (k0));     \
      const f32x4 b1 = *reinterpret_cast<const f32x4*>(gB + (size_t)(n * 32) * D_DIM + (k0) + 4); \
      _Pragma("unroll")                                                        \
      for (int j = 0; j < 4; ++j) {                                            \
        sumA[n] += a0[j] * a0[j] + a1[j] * a1[j];                              \
        sumB[n] += b0[j] * b0[j] + b1[j] * b1[j];                              \
        pa[n][j]     = (__bf16)a0[j];                                          \
        pa[n][j + 4] = (__bf16)a1[j];                                          \
        pb[n][j]     = (__bf16)b0[j];                                          \
        pb[n][j + 4] = (__bf16)b1[j];                                          \
      }                                                                        \
    }                                                                          \
  } while (0)

__global__ __launch_bounds__(256) void fused_kernel(
    const float* __restrict__ x, const float* __restrict__ cb,
    const float* __restrict__ prec, float* __restrict__ out)
{
  __shared__ __bf16 At[128 * 64];   // 16 KiB
  __shared__ __bf16 Bt[128 * 64];   // 16 KiB
  __shared__ float  xsqs[128];
  __shared__ float  csqs[128];

  const int tid = threadIdx.x;
  const int w   = tid >> 6;        // wave 0..3
  const int l   = tid & 63;
  const int wr  = w >> 1;          // wave row 0..1
  const int wc  = w & 1;           // wave col 0..1

  // bijective XCD-chunked remap (1024 % 8 == 0): per-XCD L2 working set =
  // 2MB x band + 1MB cb (f32) < 4MB.
  const int bx   = blockIdx.x;
  const int tile = (bx & 7) * 128 + (bx >> 3);
  const int tr   = tile >> 3;      // 0..127
  const int tc   = tile & 7;       // 0..7
  const int row0 = tr * 128;
  const int col0 = tc * 128;

  // staging map (round-3 verified): thread t -> row n*32 + (t>>3), granule t&7
  const int srow = tid >> 3;                 // 0..31
  const int sg   = tid & 7;                  // 16B granule index
  const int swb  = (sg ^ (srow & 7)) << 4;   // swizzled LDS granule byte
  const float* gA = x  + (size_t)(row0 + srow) * D_DIM + sg * 8;
  const float* gB = cb + (size_t)(col0 + srow) * D_DIM + sg * 8;
  char* const wAbase = (char*)At + srow * 128 + swb;
  char* const wBbase = (char*)Bt + srow * 128 + swb;

  const float p = prec[0];

  f32x4  acc[4][4] = {};
  float  sumA[4] = {}, sumB[4] = {};
  bf16x8 pa[4], pb[4];

  const int lr = l & 15;
  const int lk = l >> 4;           // 0..3

  LOADCVT(0);                      // prologue: K-tile 0

  #pragma unroll
  for (int t = 0; t < 4; ++t) {
    #pragma unroll
    for (int n = 0; n < 4; ++n) {
      *reinterpret_cast<bf16x8*>(wAbase + n * 4096) = pa[n];
      *reinterpret_cast<bf16x8*>(wBbase + n * 4096) = pb[n];
    }
    __syncthreads();

    // prefetch+convert next K-tile while this tile's MFMAs run
    if (t == 0) LOADCVT(64);
    if (t == 1) LOADCVT(128);
    if (t == 2) LOADCVT(192);

    #pragma unroll
    for (int ks = 0; ks < 2; ++ks) {
      bf16x8 af[4], bfm[4];
      #pragma unroll
      for (int f = 0; f < 4; ++f) {
        const int rar = wr * 64 + f * 16 + lr;
        af[f] = *reinterpret_cast<const bf16x8*>(
            (const char*)At + rar * 128 + ((ks * 64 + lk * 16) ^ ((rar & 7) << 4)));
        const int rbr = wc * 64 + f * 16 + lr;
        bfm[f] = *reinterpret_cast<const bf16x8*>(
            (const char*)Bt + rbr * 128 + ((ks * 64 + lk * 16) ^ ((rbr & 7) << 4)));
      }
      #pragma unroll
      for (int i = 0; i < 4; ++i)
        #pragma unroll
        for (int j = 0; j < 4; ++j)
          acc[i][j] = __builtin_amdgcn_mfma_f32_16x16x32_bf16(bfm[j], af[i], acc[i][j], 0, 0, 0);
    }
    __syncthreads();
  }

  // row norms: reduce partials over the 8 lanes (granules) sharing a row.
  // tid = srow*8 + sg -> lanes sg^1, sg^2, sg^4 are the same row.
  #pragma unroll
  for (int n = 0; n < 4; ++n) {
    float a = sumA[n], b = sumB[n];
    a += __shfl_xor(a, 1); a += __shfl_xor(a, 2); a += __shfl_xor(a, 4);
    b += __shfl_xor(b, 1); b += __shfl_xor(b, 2); b += __shfl_xor(b, 4);
    if (sg == 0) {
      xsqs[n * 32 + srow] = a;
      csqs[n * 32 + srow] = b;
    }
  }
  __syncthreads();

  // epilogue (swapped-operand D mapping):
  //   out-row = row0 + wr*64 + i*16 + (l&15)         (B-operand col = x row)
  //   out-col = col0 + wc*64 + j*16 + (l>>4)*4 + r   (A-operand row = cb idx)
  #pragma unroll
  for (int i = 0; i < 4; ++i) {
    const int rloc = wr * 64 + i * 16 + lr;
    const float xs = xsqs[rloc];
    float* orow = out + (size_t)(row0 + rloc) * K_ROWS + col0;
    #pragma unroll
    for (int j = 0; j < 4; ++j) {
      const int cloc = wc * 64 + j * 16 + lk * 4;
      const f32x4 cs = *reinterpret_cast<const f32x4*>(&csqs[cloc]);
      f32x4 v;
      #pragma unroll
      for (int r = 0; r < 4; ++r)
        v[r] = -p * (xs - 2.0f * acc[i][j][r] + cs[r]);
      *reinterpret_cast<f32x4*>(&orow[cloc]) = v;
    }
  }
}

extern "C" void kernel_launch(void* const* d_in, const int* in_sizes, int n_in,
                              void* d_out, int out_size, void* d_ws, size_t ws_size,
                              hipStream_t stream) {
  const float* x    = (const float*)d_in[0];
  const float* cb   = (const float*)d_in[1];
  const float* prec = (const float*)d_in[2];
  float* out = (float*)d_out;

  fused_kernel<<<(M_ROWS / 128) * (K_ROWS / 128), 256, 0, stream>>>(x, cb, prec, out);
}

// Round 9
// 32.763 us; speedup vs baseline: 1.2473x; 1.2473x over previous
//
#include <hip/hip_runtime.h>
#include <hip/hip_bf16.h>
#include <cstdint>

// Problem constants: B=16, T=1024, D=256, K=1024
#define M_ROWS 16384   // B*T
#define D_DIM  256
#define K_ROWS 1024

typedef __bf16 bf16x8 __attribute__((ext_vector_type(8)));
typedef __bf16 bf16x4 __attribute__((ext_vector_type(4)));
typedef float  f32x4  __attribute__((ext_vector_type(4)));

// R9 = verified R3 kernel with the MINIMAL diff that halves the accumulator:
// gemm tile 128x128 -> 128x64 (same 2x2 wave grid, wave = 64x32, acc[4][2] =
// 32 VGPR, B staging 2 passes). Goal: VGPR <= 128 -> 4 waves/SIMD (2x R5's
// measured occupancy). Prep kernel and all A-side addressing verbatim R3.

// ---------------------------------------------------------------------------
// prep: f32 -> bf16 conversion + row squared-norms (f32-exact).
// One wave per row (rows 0..M-1 = x, rows M..M+K-1 = codebook).
// Verbatim from round 3 (verified twice).
// ---------------------------------------------------------------------------
__global__ __launch_bounds__(256) void prep_kernel(
    const float* __restrict__ x, const float* __restrict__ cb,
    __bf16* __restrict__ xbf, __bf16* __restrict__ cbf,
    float* __restrict__ xsq, float* __restrict__ csq)
{
  const int row = blockIdx.x * 4 + (threadIdx.x >> 6);
  const int l   = threadIdx.x & 63;

  const float* src;
  __bf16* dst;
  float* nrm;
  if (row < M_ROWS) {
    src = x   + (size_t)row * D_DIM;
    dst = xbf + (size_t)row * D_DIM;
    nrm = xsq + row;
  } else {
    const int r = row - M_ROWS;
    src = cb  + (size_t)r * D_DIM;
    dst = cbf + (size_t)r * D_DIM;
    nrm = csq + r;
  }

  const float4 v = reinterpret_cast<const float4*>(src)[l];
  float s = v.x * v.x + v.y * v.y + v.z * v.z + v.w * v.w;

  bf16x4 h;
  h[0] = (__bf16)v.x; h[1] = (__bf16)v.y; h[2] = (__bf16)v.z; h[3] = (__bf16)v.w;
  *reinterpret_cast<bf16x4*>(dst + l * 4) = h;

  #pragma unroll
  for (int o = 32; o > 0; o >>= 1) s += __shfl_xor(s, o);
  if (l == 0) *nrm = s;
}

// ---------------------------------------------------------------------------
// GEMM: out[m,k] = -p * (xsq[m] - 2*dot(x[m],c[k]) + csq[k])
// 128x64 tile, BK=64, 4 waves (2x2): wave = 64 rows x 32 cols, acc[4][2].
// 2048 blocks.
//
// LDS: A[128][64] bf16 (16KB), B[64][64] bf16 (8KB). XOR swizzle (verified
// R3/R5): LDS[row][g] = G[row][g ^ (row&7)], g = 16B granule, row stride
// 128B. Writes: 8 distinct rows per 4-bank group (balanced). b128 fragment
// reads: lanes 0-15 sweep all 8 granules -> conflict-free.
//
// MFMA operands SWAPPED (verified): acc[i][j] = mfma(b_frag[j], a_frag[i]):
//   out-row = row0 + wr*64 + i*16 + (l&15)
//   out-col = col0 + wc*32 + j*16 + (l>>4)*4 + r   -> f32x4 stores
// ---------------------------------------------------------------------------
__global__ __launch_bounds__(256) void gemm_kernel(
    const __bf16* __restrict__ xbf, const __bf16* __restrict__ cbf,
    const float* __restrict__ xsq, const float* __restrict__ csq,
    const float* __restrict__ prec, float* __restrict__ out)
{
  __shared__ __bf16 At[128 * 64];   // 16 KiB
  __shared__ __bf16 Bt[64 * 64];    // 8 KiB

  const int tid = threadIdx.x;
  const int w   = tid >> 6;        // wave 0..3
  const int l   = tid & 63;
  const int wr  = w >> 1;          // wave row 0..1 (64 out-rows each)
  const int wc  = w & 1;           // wave col 0..1 (32 out-cols each)

  // bijective XCD-chunked remap (2048 % 8 == 0): xcd c -> tiles
  // [c*256,(c+1)*256) = 16-wide tr band x all 16 tc -> per-XCD L2 set =
  // 1MB x + 512KB cb (bf16).
  const int bx   = blockIdx.x;
  const int tile = (bx & 7) * 256 + (bx >> 3);
  const int tr   = tile >> 4;      // 0..127
  const int tc   = tile & 15;      // 0..15
  const int row0 = tr * 128;
  const int col0 = tc * 64;

  // staging (R3-verified map): thread t -> row (t>>3)+n*32, granule t&7
  const int srow = tid >> 3;                 // 0..31
  const int sg   = tid & 7;
  const int swb  = (sg ^ (srow & 7)) << 4;   // swizzled granule byte
  const __bf16* gA = xbf + (size_t)(row0 + srow) * D_DIM + sg * 8;
  const __bf16* gB = cbf + (size_t)(col0 + srow) * D_DIM + sg * 8;
  char* const wA = (char*)At + srow * 128 + swb;   // +n*4096, n=0..3
  char* const wB = (char*)Bt + srow * 128 + swb;   // +n*4096, n=0..1

  f32x4 acc[4][2] = {};

  const int lr = l & 15;
  const int lk = l >> 4;           // 0..3

  // prologue: K-tile 0 into regs
  bf16x8 ra[4], rb[2];
  #pragma unroll
  for (int n = 0; n < 4; ++n)
    ra[n] = *reinterpret_cast<const bf16x8*>(gA + (size_t)(n * 32) * D_DIM);
  #pragma unroll
  for (int n = 0; n < 2; ++n)
    rb[n] = *reinterpret_cast<const bf16x8*>(gB + (size_t)(n * 32) * D_DIM);

  #pragma unroll
  for (int t = 0; t < 4; ++t) {
    #pragma unroll
    for (int n = 0; n < 4; ++n)
      *reinterpret_cast<bf16x8*>(wA + n * 4096) = ra[n];
    #pragma unroll
    for (int n = 0; n < 2; ++n)
      *reinterpret_cast<bf16x8*>(wB + n * 4096) = rb[n];
    __syncthreads();

    // issue next K-tile's loads; they fly during the MFMA phase
    if (t < 3) {
      const int k0 = (t + 1) * 64;
      #pragma unroll
      for (int n = 0; n < 4; ++n)
        ra[n] = *reinterpret_cast<const bf16x8*>(gA + (size_t)(n * 32) * D_DIM + k0);
      #pragma unroll
      for (int n = 0; n < 2; ++n)
        rb[n] = *reinterpret_cast<const bf16x8*>(gB + (size_t)(n * 32) * D_DIM + k0);
    }

    #pragma unroll
    for (int ks = 0; ks < 2; ++ks) {
      bf16x8 af[4], bfm[2];
      #pragma unroll
      for (int f = 0; f < 4; ++f) {
        const int rar = wr * 64 + f * 16 + lr;          // 0..127
        af[f] = *reinterpret_cast<const bf16x8*>(
            (const char*)At + rar * 128 + ((ks * 64 + lk * 16) ^ ((rar & 7) << 4)));
      }
      #pragma unroll
      for (int f = 0; f < 2; ++f) {
        const int rbr = wc * 32 + f * 16 + lr;          // 0..63
        bfm[f] = *reinterpret_cast<const bf16x8*>(
            (const char*)Bt + rbr * 128 + ((ks * 64 + lk * 16) ^ ((rbr & 7) << 4)));
      }
      #pragma unroll
      for (int i = 0; i < 4; ++i)
        #pragma unroll
        for (int j = 0; j < 2; ++j)
          acc[i][j] = __builtin_amdgcn_mfma_f32_16x16x32_bf16(bfm[j], af[i], acc[i][j], 0, 0, 0);
    }
    __syncthreads();
  }

  // epilogue (swapped-operand D mapping)
  const float p = prec[0];
  #pragma unroll
  for (int i = 0; i < 4; ++i) {
    const int rowg = row0 + wr * 64 + i * 16 + lr;
    const float xs = xsq[rowg];
    float* orow = out + (size_t)rowg * K_ROWS;
    #pragma unroll
    for (int j = 0; j < 2; ++j) {
      const int colg = col0 + wc * 32 + j * 16 + lk * 4;
      const f32x4 cs = *reinterpret_cast<const f32x4*>(&csq[colg]);
      f32x4 v;
      #pragma unroll
      for (int r = 0; r < 4; ++r)
        v[r] = -p * (xs - 2.0f * acc[i][j][r] + cs[r]);
      *reinterpret_cast<f32x4*>(&orow[colg]) = v;
    }
  }
}

extern "C" void kernel_launch(void* const* d_in, const int* in_sizes, int n_in,
                              void* d_out, int out_size, void* d_ws, size_t ws_size,
                              hipStream_t stream) {
  const float* x    = (const float*)d_in[0];
  const float* cb   = (const float*)d_in[1];
  const float* prec = (const float*)d_in[2];
  float* out = (float*)d_out;

  char* ws = (char*)d_ws;
  __bf16* xbf = (__bf16*)ws;                    // 16384*256*2 = 8 MiB
  __bf16* cbf = (__bf16*)(ws + 8388608);        // 1024*256*2 = 512 KiB
  float*  xsq = (float*)(ws + 8912896);         // 16384*4 = 64 KiB
  float*  csq = (float*)(ws + 8978432);         // 1024*4 = 4 KiB

  prep_kernel<<<(M_ROWS + K_ROWS) / 4, 256, 0, stream>>>(x, cb, xbf, cbf, xsq, csq);
  gemm_kernel<<<(M_ROWS / 128) * (K_ROWS / 64), 256, 0, stream>>>(xbf, cbf, xsq, csq, prec, out);
}